// Round 9
// baseline (224.697 us; speedup 1.0000x reference)
//
#include <hip/hip_runtime.h>
#include <hip/hip_bf16.h>
#include <stdint.h>

// Problem dims (fixed)
#define MD    1024      // model dim
#define NHEAD 16
#define HDIM  64
#define BSZ   2
#define SEQL  2048
#define MROWS 4096      // BSZ*SEQL

#define SCL2E 0.18033688011112042f   // (1/sqrt(64)) * log2(e), folded into Wq/bq

typedef __bf16 bf16_t;
typedef __bf16  bf16x8 __attribute__((ext_vector_type(8)));
typedef float   f32x4  __attribute__((ext_vector_type(4)));

// Async global->LDS, 16B per lane. LDS dest is wave-uniform base (+lane*16 by HW).
__device__ __forceinline__ void gload_lds16(const void* g, void* l) {
  __builtin_amdgcn_global_load_lds((const __attribute__((address_space(1))) void*)g,
                                   (__attribute__((address_space(3))) void*)l,
                                   16, 0, 0);
}

__device__ __forceinline__ unsigned short f2bf(float f) {
  unsigned u = __builtin_bit_cast(unsigned, f);
  u += 0x7fffu + ((u >> 16) & 1u);          // round-to-nearest-even
  return (unsigned short)(u >> 16);
}

// packed 2xf32 -> 2xbf16 in one dword (src0 -> low half)
__device__ __forceinline__ unsigned cvtpk(float a, float b) {
  unsigned r;
  asm("v_cvt_pk_bf16_f32 %0, %1, %2" : "=v"(r) : "v"(a), "v"(b));
  return r;
}

// ---------------- consolidated convert ----------------
// grid 16387: [0,12288) X (4096 each), [12288,16384) W (1024 each; Wq scaled),
// 16384: bq*SCL2E -> bqs ; 16385/16386: nmask[b] = sum(1-mask[b][:])
__global__ __launch_bounds__(256)
void cvt_all(const float* __restrict__ q, const float* __restrict__ k, const float* __restrict__ v,
             const float* __restrict__ wq, const float* __restrict__ wk,
             const float* __restrict__ wv, const float* __restrict__ wo,
             const float* __restrict__ mask, const float* __restrict__ bq,
             unsigned short* __restrict__ xq, unsigned short* __restrict__ xk, unsigned short* __restrict__ xv,
             unsigned short* __restrict__ wqb, unsigned short* __restrict__ wkb,
             unsigned short* __restrict__ wvb, unsigned short* __restrict__ wob,
             float* __restrict__ bqs, float* __restrict__ nmask) {
  int bx = blockIdx.x;
  if (bx >= 16384) {
    if (bx == 16384) {                    // bqs = bq * SCL2E (1024 floats)
      int i = threadIdx.x;
      float4 val = ((const float4*)bq)[i];
      float4 o;
      o.x = val.x * SCL2E; o.y = val.y * SCL2E; o.z = val.z * SCL2E; o.w = val.w * SCL2E;
      ((float4*)bqs)[i] = o;
    } else {                              // nmask[b]
      int b = bx - 16385;
      const float* mp = mask + b * SEQL + threadIdx.x * 8;
      float s = 0.0f;
#pragma unroll
      for (int j = 0; j < 8; ++j) s += 1.0f - mp[j];
      for (int d = 1; d < 64; d <<= 1) s += __shfl_xor(s, d);
      __shared__ float wsum[4];
      if ((threadIdx.x & 63) == 0) wsum[threadIdx.x >> 6] = s;
      __syncthreads();
      if (threadIdx.x == 0) nmask[b] = wsum[0] + wsum[1] + wsum[2] + wsum[3];
    }
    return;
  }
  const float* in; unsigned short* out; int i;
  float scale = 1.0f;
  if (bx < 12288) {
    int t = bx >> 12;
    in  = (t == 0) ? q : (t == 1) ? k : v;
    out = (t == 0) ? xq : (t == 1) ? xk : xv;
    i = (bx & 4095) * 256 + threadIdx.x;
  } else {
    int t = (bx - 12288) >> 10;
    in  = (t == 0) ? wq : (t == 1) ? wk : (t == 2) ? wv : wo;
    out = (t == 0) ? wqb : (t == 1) ? wkb : (t == 2) ? wvb : wob;
    if (t == 0) scale = SCL2E;
    i = (bx & 1023) * 256 + threadIdx.x;
  }
  float4 val = ((const float4*)in)[i];
  ushort4 o;
  o.x = f2bf(val.x * scale); o.y = f2bf(val.y * scale);
  o.z = f2bf(val.z * scale); o.w = f2bf(val.w * scale);
  ((ushort4*)out)[i] = o;
}

// ---------------- GEMM: C[m,n] = sum_k A[m,k]*B[n,k] + bias[n] ----------------
// 128x128 tile, BK=64, 4 waves (2x2 of 64x64), 16x16x32 bf16 MFMA.
// LDS tiles [128 rows][128 bytes], XOR-swizzled via pre-swizzled global source.
// MODE: 0 = bf16 row-major [m][n], optional runtime row-mask;
//       1 = f32 row-major;
//       2 = bf16 V^T layout Vt[(b*1024+n)*2048+s], row-masked.
template<int MODE>
__device__ __forceinline__ void gemm_body(const bf16_t* __restrict__ A,
                                          const bf16_t* __restrict__ Bm,
                                          const float*  __restrict__ bias,
                                          const float*  __restrict__ mask,
                                          void* __restrict__ Cout, int tile) {
  __shared__ __align__(1024) char sm[32768];
  char* lsA = sm;
  char* lsB = sm + 16384;
  const int tid  = threadIdx.x;
  const int lane = tid & 63;
  const int wv   = tid >> 6;
  const int wm   = wv >> 1, wn = wv & 1;
  const int m0   = (tile >> 3) << 7;   // 32 m-tiles
  const int n0   = (tile & 7)  << 7;   // 8 n-tiles
  const int l15  = lane & 15;
  const int g16  = (lane >> 4) << 4;   // k-group byte base

  f32x4 acc[4][4] = {};

  for (int kk = 0; kk < MD; kk += 64) {
#pragma unroll
    for (int i = 0; i < 4; ++i) {
      int ch  = (wv << 2) + i;
      int o   = ch * 1024 + (lane << 4);
      int row = o >> 7;
      int scb = (o & 127) ^ ((row & 7) << 4);   // pre-swizzled source column byte
      const char* gA = (const char*)A  + (((size_t)(m0 + row) * MD + kk) << 1) + scb;
      const char* gB = (const char*)Bm + (((size_t)(n0 + row) * MD + kk) << 1) + scb;
      gload_lds16(gA, lsA + ch * 1024);
      gload_lds16(gB, lsB + ch * 1024);
    }
    __syncthreads();
#pragma unroll
    for (int s = 0; s < 2; ++s) {
      bf16x8 af[4], bfv[4];
#pragma unroll
      for (int mi = 0; mi < 4; ++mi) {
        int r  = (wm << 6) + (mi << 4) + l15;
        int cb = (g16 + (s << 6)) ^ ((r & 7) << 4);
        af[mi] = *(const bf16x8*)(lsA + (r << 7) + cb);
      }
#pragma unroll
      for (int ni = 0; ni < 4; ++ni) {
        int r  = (wn << 6) + (ni << 4) + l15;
        int cb = (g16 + (s << 6)) ^ ((r & 7) << 4);
        bfv[ni] = *(const bf16x8*)(lsB + (r << 7) + cb);
      }
      __builtin_amdgcn_s_setprio(1);
#pragma unroll
      for (int mi = 0; mi < 4; ++mi)
#pragma unroll
        for (int ni = 0; ni < 4; ++ni)
          acc[mi][ni] = __builtin_amdgcn_mfma_f32_16x16x32_bf16(af[mi], bfv[ni], acc[mi][ni], 0, 0, 0);
      __builtin_amdgcn_s_setprio(0);
    }
    __syncthreads();
  }

  // epilogue: C/D layout col = lane&15, row = (lane>>4)*4 + reg
  float bvv[4];
#pragma unroll
  for (int ni = 0; ni < 4; ++ni) bvv[ni] = bias[n0 + (wn << 6) + (ni << 4) + l15];
#pragma unroll
  for (int mi = 0; mi < 4; ++mi) {
    int m = m0 + (wm << 6) + (mi << 4) + ((lane >> 4) << 2);  // token rows m..m+3
    float4 mk = {1.0f, 1.0f, 1.0f, 1.0f};
    if constexpr (MODE == 2) mk = *(const float4*)&mask[m];
    if constexpr (MODE == 0) { if (mask) mk = *(const float4*)&mask[m]; }
#pragma unroll
    for (int ni = 0; ni < 4; ++ni) {
      int col = n0 + (wn << 6) + (ni << 4) + l15;
      if constexpr (MODE == 2) {
        int bb = m >> 11;
        int s  = m & 2047;
        ushort4 pk;
        pk.x = f2bf((acc[mi][ni][0] + bvv[ni]) * mk.x);
        pk.y = f2bf((acc[mi][ni][1] + bvv[ni]) * mk.y);
        pk.z = f2bf((acc[mi][ni][2] + bvv[ni]) * mk.z);
        pk.w = f2bf((acc[mi][ni][3] + bvv[ni]) * mk.w);
        *(ushort4*)((unsigned short*)Cout + ((size_t)(bb << 10) + col) * SEQL + s) = pk;
      } else {
#pragma unroll
        for (int r = 0; r < 4; ++r) {
          float vv = acc[mi][ni][r] + bvv[ni];
          if constexpr (MODE == 0) vv *= ((const float*)&mk)[r];
          if constexpr (MODE == 1) ((float*)Cout)[(size_t)(m + r) * MD + col] = vv;
          else                     ((bf16_t*)Cout)[(size_t)(m + r) * MD + col] = (bf16_t)vv;
        }
      }
    }
  }
}

// fused QKV (768 blocks, 3/CU, no swizzle): g selects (X,W,bias,Out).
// Q pre-scaled (bqs, mask=null), K row-masked, V transposed + row-masked.
// Two instantiations only (MODE 0 shared by Q/K; MODE 2 for V) — matches R4.
__global__ __launch_bounds__(256, 2)
void gemm_qkv(const bf16_t* __restrict__ xq, const bf16_t* __restrict__ xk, const bf16_t* __restrict__ xv,
              const bf16_t* __restrict__ wq, const bf16_t* __restrict__ wk, const bf16_t* __restrict__ wv_,
              const float* __restrict__ bqs, const float* __restrict__ bk, const float* __restrict__ bv,
              const float* __restrict__ mask,
              bf16_t* __restrict__ Qo, bf16_t* __restrict__ Ko, bf16_t* __restrict__ Vto) {
  int t = blockIdx.x & 255;
  int g = blockIdx.x >> 8;
  if (g == 2) {
    gemm_body<2>(xv, wv_, bv, mask, Vto, t);
  } else {
    const bf16_t* A  = (g == 0) ? xq : xk;
    const bf16_t* Bm = (g == 0) ? wq : wk;
    const float*  bi = (g == 0) ? bqs : bk;
    const float*  mk = (g == 0) ? nullptr : mask;
    bf16_t*       O  = (g == 0) ? Qo : Ko;
    gemm_body<0>(A, Bm, bi, mk, O, t);
  }
}

__global__ __launch_bounds__(256, 2)
void gemm_out(const bf16_t* __restrict__ A, const bf16_t* __restrict__ Bm,
              const float* __restrict__ bias, float* __restrict__ C) {
  gemm_body<1>(A, Bm, bias, nullptr, C, (int)blockIdx.x);
}

// ---------------- flash attention ----------------
// grid: 1024 = b(2)*h(16)*qtile(32), XCD-chunked swizzle; block 256 = 4 waves,
// 16 q rows/wave. K staged in LDS (dbuf, gload_lds swizzled source); V read
// DIRECTLY from global Vt (contiguous along kv; L1/L2-resident 8KB tiles,
// issued at tile top so QK^T hides latency) -> LDS read pipe carries only
// K + P (was the 46us bottleneck). LDS 24KB -> 4 blocks/CU (launch_bounds 4).
// Scale folded into Q; mask folded into K/V rows; denominator corrected by
// nmask[b]. No-max exp2 softmax. ONE barrier per KV tile (protects sK only;
// sPt is per-wave private).
__global__ __launch_bounds__(256, 4)
void attn_kernel(const bf16_t* __restrict__ Q, const bf16_t* __restrict__ K,
                 const bf16_t* __restrict__ Vt, const float* __restrict__ nmask,
                 bf16_t* __restrict__ O) {
  __shared__ __align__(1024) char sK[2][8192];
  __shared__ __align__(1024) char sPt[8192];
  int bid = (int)blockIdx.x;
  int lb  = (bid & 7) * 128 + (bid >> 3);   // 1024 = 8 x 128, bijective
  const int tid  = threadIdx.x;
  const int lane = tid & 63;
  const int wv   = tid >> 6;
  const int qt   = lb & 31;
  const int h    = (lb >> 5) & 15;
  const int b    = lb >> 9;
  const int q0   = qt << 6;
  const int l15  = lane & 15;
  const int lg   = lane >> 4;

  // Q fragment (B-operand): lane q col = l15, d = lg*8+j (+32*s)
  bf16x8 qa[2];
  {
    const bf16_t* qp = Q + (size_t)(b * SEQL + q0 + (wv << 4) + l15) * MD + h * HDIM + (lg << 3);
    qa[0] = *(const bf16x8*)qp;
    qa[1] = *(const bf16x8*)(qp + 32);
  }

  // K staging addresses (per thread): 2 chunks of 1KB (8 chunks total / 4 waves)
  const int ch0  = wv << 1;
  const int o0   = ch0 * 1024 + (lane << 4);
  const int row0 = o0 >> 7;
  const int scb0 = (o0 & 127) ^ ((row0 & 7) << 4);
  const int row1 = row0 + 8;
  const int scb1 = (o0 & 127) ^ ((row1 & 7) << 4);
  const char* Kbase = (const char*)K + (((size_t)(b * SEQL) * MD + h * HDIM) << 1);

  // V direct-load bases: Vt[(b*1024 + h*64 + d) * 2048 + kv]
  const unsigned short* VtG = (const unsigned short*)Vt + (size_t)((b << 10) + (h << 6)) * SEQL;
  const int vkoff = (lg << 3);   // per-lane kv sub-offset (elems); + s*32 per s

  f32x4 oacc[4] = {};
  float lrun = 0.0f;
  char* sPtW = sPt + (wv << 11);           // 2KB per wave (16 rows x 128B)

  auto stageK = [&](int kv0, int bsel) {
    gload_lds16(Kbase + (((size_t)(kv0 + row0) * MD) << 1) + scb0, sK[bsel] + ch0 * 1024);
    gload_lds16(Kbase + (((size_t)(kv0 + row1) * MD) << 1) + scb1, sK[bsel] + ch0 * 1024 + 1024);
  };

  stageK(0, 0);
  __syncthreads();

  for (int t = 0; t < SEQL / 64; ++t) {
    const int bsel = t & 1;
    const int kv0  = t << 6;
    if (t + 1 < SEQL / 64) stageK(kv0 + 64, bsel ^ 1);

    // issue V loads for THIS tile now; QK^T below hides the latency
    bf16x8 vreg[2][4];
#pragma unroll
    for (int s = 0; s < 2; ++s)
#pragma unroll
      for (int df = 0; df < 4; ++df)
        vreg[s][df] = *(const bf16x8*)(VtG + (size_t)((df << 4) + l15) * SEQL + kv0 + vkoff + (s << 5));

    const char* kb = sK[bsel];

    // --- S^T = K . Q^T : rows = kv, cols = q ---
    f32x4 sacc[4] = {};
#pragma unroll
    for (int s = 0; s < 2; ++s) {
      bf16x8 ka[4];
#pragma unroll
      for (int f = 0; f < 4; ++f) {
        int r  = (f << 4) + l15;
        int cb = ((lg << 4) + (s << 6)) ^ ((r & 7) << 4);
        ka[f] = *(const bf16x8*)(kb + (r << 7) + cb);
      }
      __builtin_amdgcn_s_setprio(1);
#pragma unroll
      for (int f = 0; f < 4; ++f)
        sacc[f] = __builtin_amdgcn_mfma_f32_16x16x32_bf16(ka[f], qa[s], sacc[f], 0, 0, 0);
      __builtin_amdgcn_s_setprio(0);
    }

    // --- p = exp2(z), pack to bf16, one ds_write_b64 per f ---
    {
      char* pbase = sPtW + (l15 << 7);
      int swz = (l15 & 7) << 4;
#pragma unroll
      for (int f = 0; f < 4; ++f) {
        float p0 = exp2f(sacc[f][0]);
        float p1 = exp2f(sacc[f][1]);
        float p2 = exp2f(sacc[f][2]);
        float p3 = exp2f(sacc[f][3]);
        lrun += (p0 + p1) + (p2 + p3);
        uint2 pk2;
        pk2.x = cvtpk(p0, p1);
        pk2.y = cvtpk(p2, p3);
        int boff = ((f << 5) + (lg << 3)) ^ swz;
        *(uint2*)(pbase + boff) = pk2;
      }
    }

    // --- PV: O[q][d] += Pt[q][kv] * Vt[d][kv]^T (V from registers) ---
#pragma unroll
    for (int s = 0; s < 2; ++s) {
      int cb = (lg << 4) + (s << 6);
      bf16x8 pa = *(const bf16x8*)(sPtW + (l15 << 7) + (cb ^ ((l15 & 7) << 4)));
      __builtin_amdgcn_s_setprio(1);
#pragma unroll
      for (int df = 0; df < 4; ++df)
        oacc[df] = __builtin_amdgcn_mfma_f32_16x16x32_bf16(pa, vreg[s][df], oacc[df], 0, 0, 0);
      __builtin_amdgcn_s_setprio(0);
    }
    __syncthreads();
  }

  // denominator: cross-lane reduce, subtract masked-count correction
  float nm = nmask[b];
  lrun += __shfl_xor(lrun, 16);
  lrun += __shfl_xor(lrun, 32);
  float linv = 1.0f / (lrun - nm);
#pragma unroll
  for (int r = 0; r < 4; ++r) {
    float lr = __shfl(linv, (lg << 2) + r);
    int row = b * SEQL + q0 + (wv << 4) + (lg << 2) + r;
#pragma unroll
    for (int df = 0; df < 4; ++df)
      O[(size_t)row * MD + h * HDIM + (df << 4) + l15] = (bf16_t)(oacc[df][r] * lr);
  }
}

// ---------------- launch ----------------
extern "C" void kernel_launch(void* const* d_in, const int* in_sizes, int n_in,
                              void* d_out, int out_size, void* d_ws, size_t ws_size,
                              hipStream_t stream) {
  const float* in_k = (const float*)d_in[0];
  const float* in_q = (const float*)d_in[1];
  const float* in_v = (const float*)d_in[2];
  const float* mask = (const float*)d_in[3];
  const float* Wq   = (const float*)d_in[4];
  const float* bq   = (const float*)d_in[5];
  const float* Wk   = (const float*)d_in[6];
  const float* bk   = (const float*)d_in[7];
  const float* Wv   = (const float*)d_in[8];
  const float* bv   = (const float*)d_in[9];
  const float* Wo   = (const float*)d_in[10];
  const float* bo   = (const float*)d_in[11];

  const size_t XN = (size_t)MROWS * MD;   // 4,194,304 elems
  const size_t WN = (size_t)MD * MD;      // 1,048,576 elems
  char* w = (char*)d_ws;
  size_t off = 0;
  auto alloc = [&](size_t bytes) { char* p = w + off; off += bytes; return p; };
  bf16_t* xq    = (bf16_t*)alloc(XN * 2);
  bf16_t* xk    = (bf16_t*)alloc(XN * 2);
  bf16_t* xv    = (bf16_t*)alloc(XN * 2);
  bf16_t* wqb   = (bf16_t*)alloc(WN * 2);
  bf16_t* wkb   = (bf16_t*)alloc(WN * 2);
  bf16_t* wvb   = (bf16_t*)alloc(WN * 2);
  bf16_t* wob   = (bf16_t*)alloc(WN * 2);
  bf16_t* Qp    = (bf16_t*)alloc(XN * 2);
  bf16_t* Kp    = (bf16_t*)alloc(XN * 2);
  bf16_t* Vtp   = (bf16_t*)alloc(XN * 2);  // V^T: [b][h][d][s]
  float*  bqs   = (float*)alloc(MD * 4);
  float*  nmask = (float*)alloc(16);
  bf16_t* attn  = xq;  // alias: xq is dead after gemm_qkv
  (void)ws_size;

  // single consolidated convert (3 X + 4 W + bqs + nmask)
  cvt_all<<<16387, 256, 0, stream>>>(in_q, in_k, in_v, Wq, Wk, Wv, Wo, mask, bq,
                                     (unsigned short*)xq, (unsigned short*)xk, (unsigned short*)xv,
                                     (unsigned short*)wqb, (unsigned short*)wkb,
                                     (unsigned short*)wvb, (unsigned short*)wob, bqs, nmask);

  // fused QKV projection (combined, 768 blocks = 3/CU)
  gemm_qkv<<<768, 256, 0, stream>>>(xq, xk, xv, wqb, wkb, wvb, bqs, bk, bv, mask, Qp, Kp, Vtp);

  // flash attention: 1024 blocks x 64 q rows
  attn_kernel<<<1024, 256, 0, stream>>>(Qp, Kp, Vtp, nmask, attn);

  // output projection -> fp32 d_out
  gemm_out<<<256, 256, 0, stream>>>(attn, wob, bo, (float*)d_out);
}

// Round 10
// 147.077 us; speedup vs baseline: 1.5278x; 1.5278x over previous
//
#include <hip/hip_runtime.h>
#include <hip/hip_bf16.h>
#include <stdint.h>

// Problem dims (fixed)
#define MD    1024      // model dim
#define NHEAD 16
#define HDIM  64
#define BSZ   2
#define SEQL  2048
#define MROWS 4096      // BSZ*SEQL

#define SCL2E 0.18033688011112042f   // (1/sqrt(64)) * log2(e), folded into Wq/bq

typedef __bf16 bf16_t;
typedef __bf16  bf16x8 __attribute__((ext_vector_type(8)));
typedef float   f32x4  __attribute__((ext_vector_type(4)));

// Async global->LDS, 16B per lane. LDS dest is wave-uniform base (+lane*16 by HW).
__device__ __forceinline__ void gload_lds16(const void* g, void* l) {
  __builtin_amdgcn_global_load_lds((const __attribute__((address_space(1))) void*)g,
                                   (__attribute__((address_space(3))) void*)l,
                                   16, 0, 0);
}

__device__ __forceinline__ unsigned short f2bf(float f) {
  unsigned u = __builtin_bit_cast(unsigned, f);
  u += 0x7fffu + ((u >> 16) & 1u);          // round-to-nearest-even
  return (unsigned short)(u >> 16);
}

// packed 2xf32 -> 2xbf16 in one dword (src0 -> low half)
__device__ __forceinline__ unsigned cvtpk(float a, float b) {
  unsigned r;
  asm("v_cvt_pk_bf16_f32 %0, %1, %2" : "=v"(r) : "v"(a), "v"(b));
  return r;
}

// ---------------- consolidated convert ----------------
// grid 16387: [0,12288) X (4096 each), [12288,16384) W (1024 each; Wq scaled),
// 16384: bq*SCL2E -> bqs ; 16385/16386: nmask[b] = sum(1-mask[b][:])
__global__ __launch_bounds__(256)
void cvt_all(const float* __restrict__ q, const float* __restrict__ k, const float* __restrict__ v,
             const float* __restrict__ wq, const float* __restrict__ wk,
             const float* __restrict__ wv, const float* __restrict__ wo,
             const float* __restrict__ mask, const float* __restrict__ bq,
             unsigned short* __restrict__ xq, unsigned short* __restrict__ xk, unsigned short* __restrict__ xv,
             unsigned short* __restrict__ wqb, unsigned short* __restrict__ wkb,
             unsigned short* __restrict__ wvb, unsigned short* __restrict__ wob,
             float* __restrict__ bqs, float* __restrict__ nmask) {
  int bx = blockIdx.x;
  if (bx >= 16384) {
    if (bx == 16384) {                    // bqs = bq * SCL2E (1024 floats)
      int i = threadIdx.x;
      float4 val = ((const float4*)bq)[i];
      float4 o;
      o.x = val.x * SCL2E; o.y = val.y * SCL2E; o.z = val.z * SCL2E; o.w = val.w * SCL2E;
      ((float4*)bqs)[i] = o;
    } else {                              // nmask[b]
      int b = bx - 16385;
      const float* mp = mask + b * SEQL + threadIdx.x * 8;
      float s = 0.0f;
#pragma unroll
      for (int j = 0; j < 8; ++j) s += 1.0f - mp[j];
      for (int d = 1; d < 64; d <<= 1) s += __shfl_xor(s, d);
      __shared__ float wsum[4];
      if ((threadIdx.x & 63) == 0) wsum[threadIdx.x >> 6] = s;
      __syncthreads();
      if (threadIdx.x == 0) nmask[b] = wsum[0] + wsum[1] + wsum[2] + wsum[3];
    }
    return;
  }
  const float* in; unsigned short* out; int i;
  float scale = 1.0f;
  if (bx < 12288) {
    int t = bx >> 12;
    in  = (t == 0) ? q : (t == 1) ? k : v;
    out = (t == 0) ? xq : (t == 1) ? xk : xv;
    i = (bx & 4095) * 256 + threadIdx.x;
  } else {
    int t = (bx - 12288) >> 10;
    in  = (t == 0) ? wq : (t == 1) ? wk : (t == 2) ? wv : wo;
    out = (t == 0) ? wqb : (t == 1) ? wkb : (t == 2) ? wvb : wob;
    if (t == 0) scale = SCL2E;
    i = (bx & 1023) * 256 + threadIdx.x;
  }
  float4 val = ((const float4*)in)[i];
  ushort4 o;
  o.x = f2bf(val.x * scale); o.y = f2bf(val.y * scale);
  o.z = f2bf(val.z * scale); o.w = f2bf(val.w * scale);
  ((ushort4*)out)[i] = o;
}

// ---------------- GEMM: C[m,n] = sum_k A[m,k]*B[n,k] + bias[n] ----------------
// 128x128 tile, BK=64, 4 waves (2x2 of 64x64), 16x16x32 bf16 MFMA.
// LDS tiles [128 rows][128 bytes], XOR-swizzled via pre-swizzled global source.
// MODE: 0 = bf16 row-major [m][n], optional runtime row-mask;
//       1 = f32 row-major;
//       2 = bf16 V^T layout Vt[(b*1024+n)*2048+s], row-masked.
template<int MODE>
__device__ __forceinline__ void gemm_body(const bf16_t* __restrict__ A,
                                          const bf16_t* __restrict__ Bm,
                                          const float*  __restrict__ bias,
                                          const float*  __restrict__ mask,
                                          void* __restrict__ Cout, int tile) {
  __shared__ __align__(1024) char sm[32768];
  char* lsA = sm;
  char* lsB = sm + 16384;
  const int tid  = threadIdx.x;
  const int lane = tid & 63;
  const int wv   = tid >> 6;
  const int wm   = wv >> 1, wn = wv & 1;
  const int m0   = (tile >> 3) << 7;   // 32 m-tiles
  const int n0   = (tile & 7)  << 7;   // 8 n-tiles
  const int l15  = lane & 15;
  const int g16  = (lane >> 4) << 4;   // k-group byte base

  f32x4 acc[4][4] = {};

  for (int kk = 0; kk < MD; kk += 64) {
#pragma unroll
    for (int i = 0; i < 4; ++i) {
      int ch  = (wv << 2) + i;
      int o   = ch * 1024 + (lane << 4);
      int row = o >> 7;
      int scb = (o & 127) ^ ((row & 7) << 4);   // pre-swizzled source column byte
      const char* gA = (const char*)A  + (((size_t)(m0 + row) * MD + kk) << 1) + scb;
      const char* gB = (const char*)Bm + (((size_t)(n0 + row) * MD + kk) << 1) + scb;
      gload_lds16(gA, lsA + ch * 1024);
      gload_lds16(gB, lsB + ch * 1024);
    }
    __syncthreads();
#pragma unroll
    for (int s = 0; s < 2; ++s) {
      bf16x8 af[4], bfv[4];
#pragma unroll
      for (int mi = 0; mi < 4; ++mi) {
        int r  = (wm << 6) + (mi << 4) + l15;
        int cb = (g16 + (s << 6)) ^ ((r & 7) << 4);
        af[mi] = *(const bf16x8*)(lsA + (r << 7) + cb);
      }
#pragma unroll
      for (int ni = 0; ni < 4; ++ni) {
        int r  = (wn << 6) + (ni << 4) + l15;
        int cb = (g16 + (s << 6)) ^ ((r & 7) << 4);
        bfv[ni] = *(const bf16x8*)(lsB + (r << 7) + cb);
      }
      __builtin_amdgcn_s_setprio(1);
#pragma unroll
      for (int mi = 0; mi < 4; ++mi)
#pragma unroll
        for (int ni = 0; ni < 4; ++ni)
          acc[mi][ni] = __builtin_amdgcn_mfma_f32_16x16x32_bf16(af[mi], bfv[ni], acc[mi][ni], 0, 0, 0);
      __builtin_amdgcn_s_setprio(0);
    }
    __syncthreads();
  }

  // epilogue: C/D layout col = lane&15, row = (lane>>4)*4 + reg
  float bvv[4];
#pragma unroll
  for (int ni = 0; ni < 4; ++ni) bvv[ni] = bias[n0 + (wn << 6) + (ni << 4) + l15];
#pragma unroll
  for (int mi = 0; mi < 4; ++mi) {
    int m = m0 + (wm << 6) + (mi << 4) + ((lane >> 4) << 2);  // token rows m..m+3
    float4 mk = {1.0f, 1.0f, 1.0f, 1.0f};
    if constexpr (MODE == 2) mk = *(const float4*)&mask[m];
    if constexpr (MODE == 0) { if (mask) mk = *(const float4*)&mask[m]; }
#pragma unroll
    for (int ni = 0; ni < 4; ++ni) {
      int col = n0 + (wn << 6) + (ni << 4) + l15;
      if constexpr (MODE == 2) {
        int bb = m >> 11;
        int s  = m & 2047;
        ushort4 pk;
        pk.x = f2bf((acc[mi][ni][0] + bvv[ni]) * mk.x);
        pk.y = f2bf((acc[mi][ni][1] + bvv[ni]) * mk.y);
        pk.z = f2bf((acc[mi][ni][2] + bvv[ni]) * mk.z);
        pk.w = f2bf((acc[mi][ni][3] + bvv[ni]) * mk.w);
        *(ushort4*)((unsigned short*)Cout + ((size_t)(bb << 10) + col) * SEQL + s) = pk;
      } else {
#pragma unroll
        for (int r = 0; r < 4; ++r) {
          float vv = acc[mi][ni][r] + bvv[ni];
          if constexpr (MODE == 0) vv *= ((const float*)&mk)[r];
          if constexpr (MODE == 1) ((float*)Cout)[(size_t)(m + r) * MD + col] = vv;
          else                     ((bf16_t*)Cout)[(size_t)(m + r) * MD + col] = (bf16_t)vv;
        }
      }
    }
  }
}

// fused QKV (768 blocks, 3/CU, no swizzle): g selects (X,W,bias,Out).
// Q pre-scaled (bqs, mask=null), K row-masked, V transposed + row-masked.
// Two instantiations only (MODE 0 shared by Q/K; MODE 2 for V) — measured 71us config (R9).
__global__ __launch_bounds__(256, 2)
void gemm_qkv(const bf16_t* __restrict__ xq, const bf16_t* __restrict__ xk, const bf16_t* __restrict__ xv,
              const bf16_t* __restrict__ wq, const bf16_t* __restrict__ wk, const bf16_t* __restrict__ wv_,
              const float* __restrict__ bqs, const float* __restrict__ bk, const float* __restrict__ bv,
              const float* __restrict__ mask,
              bf16_t* __restrict__ Qo, bf16_t* __restrict__ Ko, bf16_t* __restrict__ Vto) {
  int t = blockIdx.x & 255;
  int g = blockIdx.x >> 8;
  if (g == 2) {
    gemm_body<2>(xv, wv_, bv, mask, Vto, t);
  } else {
    const bf16_t* A  = (g == 0) ? xq : xk;
    const bf16_t* Bm = (g == 0) ? wq : wk;
    const float*  bi = (g == 0) ? bqs : bk;
    const float*  mk = (g == 0) ? nullptr : mask;
    bf16_t*       O  = (g == 0) ? Qo : Ko;
    gemm_body<0>(A, Bm, bi, mk, O, t);
  }
}

__global__ __launch_bounds__(256, 2)
void gemm_out(const bf16_t* __restrict__ A, const bf16_t* __restrict__ Bm,
              const float* __restrict__ bias, float* __restrict__ C) {
  gemm_body<1>(A, Bm, bias, nullptr, C, (int)blockIdx.x);
}

// ---------------- flash attention, KV-split across waves ----------------
// grid 1024 = b(2)*h(16)*qtile(32) (XCD swizzle); block 128 = 2 waves.
// Block owns 64 q rows; EACH wave processes all 64 q (4 frags) over its own
// alternating 64-kv tiles (16 tiles/wave) with PRIVATE K/V^T LDS buffers and
// private P buffer -> ZERO barriers in the main loop; per-wave counted
// vmcnt(8)/vmcnt(0) replaces barrier drains. No-max softmax makes kv-partials
// additive: one final LDS reduction (O-partials [d][q] f32 swizzled + l).
// Scale folded into Q, mask folded into K/V rows, nmask fixes denominator.
__global__ __launch_bounds__(128, 2)
void attn_kernel(const bf16_t* __restrict__ Q, const bf16_t* __restrict__ K,
                 const bf16_t* __restrict__ Vt, const float* __restrict__ nmask,
                 bf16_t* __restrict__ O) {
  __shared__ __align__(1024) char sKV[2][16384];  // per-wave: K 8KB + V^T 8KB; later O-partial [64d][256B]
  __shared__ __align__(1024) char sPt[2][2048];   // per-wave P^T [16 q][128B]; later l-partials
  int bid = (int)blockIdx.x;
  int lb  = (bid & 7) * 128 + (bid >> 3);   // 1024 = 8 x 128, bijective
  const int tid  = threadIdx.x;
  const int lane = tid & 63;
  const int wv   = tid >> 6;                // 0 or 1
  const int qt   = lb & 31;
  const int h    = (lb >> 5) & 15;
  const int b    = lb >> 9;
  const int q0   = qt << 6;
  const int l15  = lane & 15;
  const int lg   = lane >> 4;

  // Q fragments (B-operand), 4 frags of 16 q: lane q col = l15, d = lg*8+j (+32*s)
  bf16x8 qa[4][2];
#pragma unroll
  for (int qc = 0; qc < 4; ++qc) {
    const bf16_t* qp = Q + (size_t)(b * SEQL + q0 + (qc << 4) + l15) * MD + h * HDIM + (lg << 3);
    qa[qc][0] = *(const bf16x8*)qp;
    qa[qc][1] = *(const bf16x8*)(qp + 32);
  }

  // staging: each wave stages its own 8KB K + 8KB V^T tile (16 x 1KB chunks)
  const int o      = lane << 4;
  const int subrow = o >> 7;                       // 0..7 within chunk
  const int scb    = (o & 127) ^ ((subrow & 7) << 4);
  const char* Kbase = (const char*)K + (((size_t)(b * SEQL) * MD + h * HDIM) << 1);
  const char* VtB   = (const char*)Vt + (((size_t)((b << 10) + (h << 6)) * SEQL) << 1);
  char* sK = sKV[wv];
  char* sV = sKV[wv] + 8192;
  char* sP = sPt[wv];

  f32x4 oacc[4][4] = {};
  float lrun[4] = {0.0f, 0.0f, 0.0f, 0.0f};
  char* pbase = sP + (l15 << 7);
  const int swz = (l15 & 7) << 4;

  for (int i = 0; i < 16; ++i) {
    const int kv0 = ((i << 1) + wv) << 6;
    // stage K chunks (8), then V chunks (8)
#pragma unroll
    for (int c = 0; c < 8; ++c)
      gload_lds16(Kbase + (((size_t)(kv0 + (c << 3) + subrow) * MD) << 1) + scb, sK + c * 1024);
#pragma unroll
    for (int c = 0; c < 8; ++c)
      gload_lds16(VtB + (size_t)((c << 3) + subrow) * (SEQL * 2) + kv0 * 2 + scb, sV + c * 1024);

    asm volatile("s_waitcnt vmcnt(8)" ::: "memory");   // K ready (8 V still in flight)
    __builtin_amdgcn_sched_barrier(0);

    // --- S^T = K . Q^T : rows = kv, cols = q (per q-frag) ---
    f32x4 sacc[4][4];
#pragma unroll
    for (int qc = 0; qc < 4; ++qc)
#pragma unroll
      for (int f = 0; f < 4; ++f) sacc[qc][f] = (f32x4){0.f, 0.f, 0.f, 0.f};
#pragma unroll
    for (int s = 0; s < 2; ++s) {
      bf16x8 ka[4];
#pragma unroll
      for (int f = 0; f < 4; ++f) {
        int r  = (f << 4) + l15;
        int cb = ((lg << 4) + (s << 6)) ^ ((r & 7) << 4);
        ka[f] = *(const bf16x8*)(sK + (r << 7) + cb);
      }
      __builtin_amdgcn_s_setprio(1);
#pragma unroll
      for (int f = 0; f < 4; ++f)
#pragma unroll
        for (int qc = 0; qc < 4; ++qc)
          sacc[qc][f] = __builtin_amdgcn_mfma_f32_16x16x32_bf16(ka[f], qa[qc][s], sacc[qc][f], 0, 0, 0);
      __builtin_amdgcn_s_setprio(0);
    }

    asm volatile("s_waitcnt vmcnt(0)" ::: "memory");   // V ready
    __builtin_amdgcn_sched_barrier(0);
    bf16x8 vb[2][4];
#pragma unroll
    for (int s = 0; s < 2; ++s)
#pragma unroll
      for (int df = 0; df < 4; ++df) {
        int d  = (df << 4) + l15;
        int cb = ((lg << 4) + (s << 6)) ^ ((d & 7) << 4);
        vb[s][df] = *(const bf16x8*)(sV + (d << 7) + cb);
      }

    // --- per q-frag: softmax (no max-subtract) -> P -> PV ---
#pragma unroll
    for (int qc = 0; qc < 4; ++qc) {
#pragma unroll
      for (int f = 0; f < 4; ++f) {
        float p0 = exp2f(sacc[qc][f][0]);
        float p1 = exp2f(sacc[qc][f][1]);
        float p2 = exp2f(sacc[qc][f][2]);
        float p3 = exp2f(sacc[qc][f][3]);
        lrun[qc] += (p0 + p1) + (p2 + p3);
        uint2 pk2;
        pk2.x = cvtpk(p0, p1);
        pk2.y = cvtpk(p2, p3);
        *(uint2*)(pbase + (((f << 5) + (lg << 3)) ^ swz)) = pk2;
      }
#pragma unroll
      for (int s = 0; s < 2; ++s) {
        bf16x8 pa = *(const bf16x8*)(pbase + (((lg << 4) + (s << 6)) ^ swz));
        __builtin_amdgcn_s_setprio(1);
#pragma unroll
        for (int df = 0; df < 4; ++df)
          oacc[qc][df] = __builtin_amdgcn_mfma_f32_16x16x32_bf16(pa, vb[s][df], oacc[qc][df], 0, 0, 0);
        __builtin_amdgcn_s_setprio(0);
      }
    }
  }

  // intra-wave l reduce across lg groups (per qc, valid at every lane's l15)
#pragma unroll
  for (int qc = 0; qc < 4; ++qc) {
    lrun[qc] += __shfl_xor(lrun[qc], 16);
    lrun[qc] += __shfl_xor(lrun[qc], 32);
  }

  // write O-partial (f32, [64 d][256B q], XOR-swizzled) into own sKV region
#pragma unroll
  for (int qc = 0; qc < 4; ++qc)
#pragma unroll
    for (int df = 0; df < 4; ++df) {
      int d  = (df << 4) + l15;
      int ob = (d << 8) + ((((qc << 6) + (lg << 4))) ^ ((d & 7) << 4));
      *(f32x4*)(sKV[wv] + ob) = oacc[qc][df];
    }
  // write l-partials into own sPt
  if (lane < 16) {
#pragma unroll
    for (int qc = 0; qc < 4; ++qc) ((float*)sPt[wv])[(qc << 4) + l15] = lrun[qc];
  }
  __syncthreads();

  // cross-wave combine: l, then each wave stores its 2 q-frags
  const float nm = nmask[b];
  float linv[4];
#pragma unroll
  for (int qc = 0; qc < 4; ++qc) {
    float lo = ((const float*)sPt[wv ^ 1])[(qc << 4) + l15];
    linv[qc] = 1.0f / (lrun[qc] + lo - nm);
  }
#pragma unroll
  for (int j = 0; j < 2; ++j) {
    int qc = (wv << 1) + j;
#pragma unroll
    for (int df = 0; df < 4; ++df) {
      int d  = (df << 4) + l15;
      int ob = (d << 8) + ((((qc << 6) + (lg << 4))) ^ ((d & 7) << 4));
      f32x4 a0 = *(const f32x4*)(sKV[0] + ob);
      f32x4 a1 = *(const f32x4*)(sKV[1] + ob);
#pragma unroll
      for (int r = 0; r < 4; ++r) {
        float lr = __shfl(linv[qc], (lg << 2) + r);
        int row = b * SEQL + q0 + (qc << 4) + (lg << 2) + r;
        O[(size_t)row * MD + h * HDIM + d] = (bf16_t)((a0[r] + a1[r]) * lr);
      }
    }
  }
}

// ---------------- launch ----------------
extern "C" void kernel_launch(void* const* d_in, const int* in_sizes, int n_in,
                              void* d_out, int out_size, void* d_ws, size_t ws_size,
                              hipStream_t stream) {
  const float* in_k = (const float*)d_in[0];
  const float* in_q = (const float*)d_in[1];
  const float* in_v = (const float*)d_in[2];
  const float* mask = (const float*)d_in[3];
  const float* Wq   = (const float*)d_in[4];
  const float* bq   = (const float*)d_in[5];
  const float* Wk   = (const float*)d_in[6];
  const float* bk   = (const float*)d_in[7];
  const float* Wv   = (const float*)d_in[8];
  const float* bv   = (const float*)d_in[9];
  const float* Wo   = (const float*)d_in[10];
  const float* bo   = (const float*)d_in[11];

  const size_t XN = (size_t)MROWS * MD;   // 4,194,304 elems
  const size_t WN = (size_t)MD * MD;      // 1,048,576 elems
  char* w = (char*)d_ws;
  size_t off = 0;
  auto alloc = [&](size_t bytes) { char* p = w + off; off += bytes; return p; };
  bf16_t* xq    = (bf16_t*)alloc(XN * 2);
  bf16_t* xk    = (bf16_t*)alloc(XN * 2);
  bf16_t* xv    = (bf16_t*)alloc(XN * 2);
  bf16_t* wqb   = (bf16_t*)alloc(WN * 2);
  bf16_t* wkb   = (bf16_t*)alloc(WN * 2);
  bf16_t* wvb   = (bf16_t*)alloc(WN * 2);
  bf16_t* wob   = (bf16_t*)alloc(WN * 2);
  bf16_t* Qp    = (bf16_t*)alloc(XN * 2);
  bf16_t* Kp    = (bf16_t*)alloc(XN * 2);
  bf16_t* Vtp   = (bf16_t*)alloc(XN * 2);  // V^T: [b][h][d][s]
  float*  bqs   = (float*)alloc(MD * 4);
  float*  nmask = (float*)alloc(16);
  bf16_t* attn  = xq;  // alias: xq is dead after gemm_qkv
  (void)ws_size;

  // single consolidated convert (3 X + 4 W + bqs + nmask)
  cvt_all<<<16387, 256, 0, stream>>>(in_q, in_k, in_v, Wq, Wk, Wv, Wo, mask, bq,
                                     (unsigned short*)xq, (unsigned short*)xk, (unsigned short*)xv,
                                     (unsigned short*)wqb, (unsigned short*)wkb,
                                     (unsigned short*)wvb, (unsigned short*)wob, bqs, nmask);

  // fused QKV projection (combined, 768 blocks = 3/CU) — measured 71us config
  gemm_qkv<<<768, 256, 0, stream>>>(xq, xk, xv, wqb, wkb, wvb, bqs, bk, bv, mask, Qp, Kp, Vtp);

  // flash attention: 1024 blocks x 2 waves, KV-split
  attn_kernel<<<1024, 128, 0, stream>>>(Qp, Kp, Vtp, nmask, attn);

  // output projection -> fp32 d_out
  gemm_out<<<256, 256, 0, stream>>>(attn, wob, bo, (float*)d_out);
}

// Round 11
// 144.171 us; speedup vs baseline: 1.5585x; 1.0202x over previous
//
#include <hip/hip_runtime.h>
#include <hip/hip_bf16.h>
#include <stdint.h>

// Problem dims (fixed)
#define MD    1024      // model dim
#define NHEAD 16
#define HDIM  64
#define BSZ   2
#define SEQL  2048
#define MROWS 4096      // BSZ*SEQL

#define SCL2E 0.18033688011112042f   // (1/sqrt(64)) * log2(e), folded into Wq/bq

typedef __bf16 bf16_t;
typedef __bf16  bf16x8 __attribute__((ext_vector_type(8)));
typedef float   f32x4  __attribute__((ext_vector_type(4)));

// Async global->LDS, 16B per lane. LDS dest is wave-uniform base (+lane*16 by HW).
__device__ __forceinline__ void gload_lds16(const void* g, void* l) {
  __builtin_amdgcn_global_load_lds((const __attribute__((address_space(1))) void*)g,
                                   (__attribute__((address_space(3))) void*)l,
                                   16, 0, 0);
}

__device__ __forceinline__ unsigned short f2bf(float f) {
  unsigned u = __builtin_bit_cast(unsigned, f);
  u += 0x7fffu + ((u >> 16) & 1u);          // round-to-nearest-even
  return (unsigned short)(u >> 16);
}

// packed 2xf32 -> 2xbf16 in one dword (src0 -> low half)
__device__ __forceinline__ unsigned cvtpk(float a, float b) {
  unsigned r;
  asm("v_cvt_pk_bf16_f32 %0, %1, %2" : "=v"(r) : "v"(a), "v"(b));
  return r;
}

// ---------------- consolidated convert ----------------
// grid 16387: [0,12288) X (4096 each), [12288,16384) W (1024 each; Wq scaled),
// 16384: bq*SCL2E -> bqs ; 16385/16386: nmask[b] = sum(1-mask[b][:])
__global__ __launch_bounds__(256)
void cvt_all(const float* __restrict__ q, const float* __restrict__ k, const float* __restrict__ v,
             const float* __restrict__ wq, const float* __restrict__ wk,
             const float* __restrict__ wv, const float* __restrict__ wo,
             const float* __restrict__ mask, const float* __restrict__ bq,
             unsigned short* __restrict__ xq, unsigned short* __restrict__ xk, unsigned short* __restrict__ xv,
             unsigned short* __restrict__ wqb, unsigned short* __restrict__ wkb,
             unsigned short* __restrict__ wvb, unsigned short* __restrict__ wob,
             float* __restrict__ bqs, float* __restrict__ nmask) {
  int bx = blockIdx.x;
  if (bx >= 16384) {
    if (bx == 16384) {                    // bqs = bq * SCL2E (1024 floats)
      int i = threadIdx.x;
      float4 val = ((const float4*)bq)[i];
      float4 o;
      o.x = val.x * SCL2E; o.y = val.y * SCL2E; o.z = val.z * SCL2E; o.w = val.w * SCL2E;
      ((float4*)bqs)[i] = o;
    } else {                              // nmask[b]
      int b = bx - 16385;
      const float* mp = mask + b * SEQL + threadIdx.x * 8;
      float s = 0.0f;
#pragma unroll
      for (int j = 0; j < 8; ++j) s += 1.0f - mp[j];
      for (int d = 1; d < 64; d <<= 1) s += __shfl_xor(s, d);
      __shared__ float wsum[4];
      if ((threadIdx.x & 63) == 0) wsum[threadIdx.x >> 6] = s;
      __syncthreads();
      if (threadIdx.x == 0) nmask[b] = wsum[0] + wsum[1] + wsum[2] + wsum[3];
    }
    return;
  }
  const float* in; unsigned short* out; int i;
  float scale = 1.0f;
  if (bx < 12288) {
    int t = bx >> 12;
    in  = (t == 0) ? q : (t == 1) ? k : v;
    out = (t == 0) ? xq : (t == 1) ? xk : xv;
    i = (bx & 4095) * 256 + threadIdx.x;
  } else {
    int t = (bx - 12288) >> 10;
    in  = (t == 0) ? wq : (t == 1) ? wk : (t == 2) ? wv : wo;
    out = (t == 0) ? wqb : (t == 1) ? wkb : (t == 2) ? wvb : wob;
    if (t == 0) scale = SCL2E;
    i = (bx & 1023) * 256 + threadIdx.x;
  }
  float4 val = ((const float4*)in)[i];
  ushort4 o;
  o.x = f2bf(val.x * scale); o.y = f2bf(val.y * scale);
  o.z = f2bf(val.z * scale); o.w = f2bf(val.w * scale);
  ((ushort4*)out)[i] = o;
}

// ---------------- GEMM: C[m,n] = sum_k A[m,k]*B[n,k] + bias[n] ----------------
// 128x128 tile, BK=64, 4 waves (2x2 of 64x64), 16x16x32 bf16 MFMA.
// LDS tiles [128 rows][128 bytes], XOR-swizzled via pre-swizzled global source.
// MODE: 0 = bf16 row-major [m][n], optional runtime row-mask;
//       1 = f32 row-major;
//       2 = bf16 V in PV-MFMA fragment layout, row-masked:
//           elem ofs = ((((b*16+h)*32+tile)*2+s2)*4+df)*512 + (lg*16+l15)*8 + j
//           (tile=kv>>6, s2=(kv>>5)&1, lg=(kv>>3)&3, j=kv&7, df=(d&63)>>4, l15=d&15)
template<int MODE>
__device__ __forceinline__ void gemm_body(const bf16_t* __restrict__ A,
                                          const bf16_t* __restrict__ Bm,
                                          const float*  __restrict__ bias,
                                          const float*  __restrict__ mask,
                                          void* __restrict__ Cout, int tile) {
  __shared__ __align__(1024) char sm[32768];
  char* lsA = sm;
  char* lsB = sm + 16384;
  const int tid  = threadIdx.x;
  const int lane = tid & 63;
  const int wv   = tid >> 6;
  const int wm   = wv >> 1, wn = wv & 1;
  const int m0   = (tile >> 3) << 7;   // 32 m-tiles
  const int n0   = (tile & 7)  << 7;   // 8 n-tiles
  const int l15  = lane & 15;
  const int g16  = (lane >> 4) << 4;   // k-group byte base

  f32x4 acc[4][4] = {};

  for (int kk = 0; kk < MD; kk += 64) {
#pragma unroll
    for (int i = 0; i < 4; ++i) {
      int ch  = (wv << 2) + i;
      int o   = ch * 1024 + (lane << 4);
      int row = o >> 7;
      int scb = (o & 127) ^ ((row & 7) << 4);   // pre-swizzled source column byte
      const char* gA = (const char*)A  + (((size_t)(m0 + row) * MD + kk) << 1) + scb;
      const char* gB = (const char*)Bm + (((size_t)(n0 + row) * MD + kk) << 1) + scb;
      gload_lds16(gA, lsA + ch * 1024);
      gload_lds16(gB, lsB + ch * 1024);
    }
    __syncthreads();
#pragma unroll
    for (int s = 0; s < 2; ++s) {
      bf16x8 af[4], bfv[4];
#pragma unroll
      for (int mi = 0; mi < 4; ++mi) {
        int r  = (wm << 6) + (mi << 4) + l15;
        int cb = (g16 + (s << 6)) ^ ((r & 7) << 4);
        af[mi] = *(const bf16x8*)(lsA + (r << 7) + cb);
      }
#pragma unroll
      for (int ni = 0; ni < 4; ++ni) {
        int r  = (wn << 6) + (ni << 4) + l15;
        int cb = (g16 + (s << 6)) ^ ((r & 7) << 4);
        bfv[ni] = *(const bf16x8*)(lsB + (r << 7) + cb);
      }
      __builtin_amdgcn_s_setprio(1);
#pragma unroll
      for (int mi = 0; mi < 4; ++mi)
#pragma unroll
        for (int ni = 0; ni < 4; ++ni)
          acc[mi][ni] = __builtin_amdgcn_mfma_f32_16x16x32_bf16(af[mi], bfv[ni], acc[mi][ni], 0, 0, 0);
      __builtin_amdgcn_s_setprio(0);
    }
    __syncthreads();
  }

  // epilogue: C/D layout col = lane&15, row = (lane>>4)*4 + reg
  float bvv[4];
#pragma unroll
  for (int ni = 0; ni < 4; ++ni) bvv[ni] = bias[n0 + (wn << 6) + (ni << 4) + l15];
#pragma unroll
  for (int mi = 0; mi < 4; ++mi) {
    int m = m0 + (wm << 6) + (mi << 4) + ((lane >> 4) << 2);  // token rows m..m+3
    float4 mk = {1.0f, 1.0f, 1.0f, 1.0f};
    if constexpr (MODE == 2) mk = *(const float4*)&mask[m];
    if constexpr (MODE == 0) { if (mask) mk = *(const float4*)&mask[m]; }
#pragma unroll
    for (int ni = 0; ni < 4; ++ni) {
      int col = n0 + (wn << 6) + (ni << 4) + l15;
      if constexpr (MODE == 2) {
        int bb   = m >> 11;
        int kv   = m & 2047;
        int tl   = kv >> 6;
        int s2   = (kv >> 5) & 1;
        int lgv  = (kv >> 3) & 3;
        int j0   = m & 4;
        int hh   = col >> 6;
        int dd   = col & 63;
        size_t e = ((((size_t)((bb << 4) + hh) * 32 + tl) * 2 + s2) * 4 + (dd >> 4)) * 512
                 + (size_t)(((lgv << 4) + (dd & 15)) << 3) + j0;
        ushort4 pk;
        pk.x = f2bf((acc[mi][ni][0] + bvv[ni]) * mk.x);
        pk.y = f2bf((acc[mi][ni][1] + bvv[ni]) * mk.y);
        pk.z = f2bf((acc[mi][ni][2] + bvv[ni]) * mk.z);
        pk.w = f2bf((acc[mi][ni][3] + bvv[ni]) * mk.w);
        *(ushort4*)((unsigned short*)Cout + e) = pk;
      } else {
#pragma unroll
        for (int r = 0; r < 4; ++r) {
          float vv = acc[mi][ni][r] + bvv[ni];
          if constexpr (MODE == 0) vv *= ((const float*)&mk)[r];
          if constexpr (MODE == 1) ((float*)Cout)[(size_t)(m + r) * MD + col] = vv;
          else                     ((bf16_t*)Cout)[(size_t)(m + r) * MD + col] = (bf16_t)vv;
        }
      }
    }
  }
}

// fused QKV (768 blocks, 3/CU, no swizzle): g selects (X,W,bias,Out).
// Q pre-scaled (bqs, mask=null), K row-masked, V fragment-layout + row-masked.
__global__ __launch_bounds__(256, 2)
void gemm_qkv(const bf16_t* __restrict__ xq, const bf16_t* __restrict__ xk, const bf16_t* __restrict__ xv,
              const bf16_t* __restrict__ wq, const bf16_t* __restrict__ wk, const bf16_t* __restrict__ wv_,
              const float* __restrict__ bqs, const float* __restrict__ bk, const float* __restrict__ bv,
              const float* __restrict__ mask,
              bf16_t* __restrict__ Qo, bf16_t* __restrict__ Ko, bf16_t* __restrict__ Vfo) {
  int t = blockIdx.x & 255;
  int g = blockIdx.x >> 8;
  if (g == 2) {
    gemm_body<2>(xv, wv_, bv, mask, Vfo, t);
  } else {
    const bf16_t* A  = (g == 0) ? xq : xk;
    const bf16_t* Bm = (g == 0) ? wq : wk;
    const float*  bi = (g == 0) ? bqs : bk;
    const float*  mk = (g == 0) ? nullptr : mask;
    bf16_t*       O  = (g == 0) ? Qo : Ko;
    gemm_body<0>(A, Bm, bi, mk, O, t);
  }
}

__global__ __launch_bounds__(256, 2)
void gemm_out(const bf16_t* __restrict__ A, const bf16_t* __restrict__ Bm,
              const float* __restrict__ bias, float* __restrict__ C) {
  gemm_body<1>(A, Bm, bias, nullptr, C, (int)blockIdx.x);
}

// ---------------- flash attention, KV-split + per-wave counted pipeline -----
// grid 1024 = b(2)*h(16)*qtile(32) (XCD swizzle); block 128 = 2 waves.
// Block owns 64 q; each wave processes alternating 64-kv tiles (16/wave),
// barrier-free. Per wave: K LDS double-buffered, staged one tile ahead
// (vmcnt(16) waits only the current tile's K; next K + V stay in flight);
// V loaded to REGISTERS from fragment-layout Vf (coalesced dwordx4), issued
// one tile ahead at the loop tail. P ping-pong (2 buffers) with SM/PV
// interleave breaks the ds_write->ds_read RAW stall.
__global__ __launch_bounds__(128, 2)
void attn_kernel(const bf16_t* __restrict__ Q, const bf16_t* __restrict__ K,
                 const bf16_t* __restrict__ Vf, const float* __restrict__ nmask,
                 bf16_t* __restrict__ O) {
  __shared__ __align__(1024) char sK[2][2][8192];   // [wave][dbuf]
  __shared__ __align__(1024) char sPt[2][2][2048];  // [wave][pingpong]
  int bid = (int)blockIdx.x;
  int lb  = (bid & 7) * 128 + (bid >> 3);   // 1024 = 8 x 128, bijective
  const int tid  = threadIdx.x;
  const int lane = tid & 63;
  const int wv   = tid >> 6;                // 0 or 1
  const int qt   = lb & 31;
  const int h    = (lb >> 5) & 15;
  const int b    = lb >> 9;
  const int q0   = qt << 6;
  const int l15  = lane & 15;
  const int lg   = lane >> 4;

  // Q fragments (B-operand), 4 frags of 16 q
  bf16x8 qa[4][2];
#pragma unroll
  for (int qc = 0; qc < 4; ++qc) {
    const bf16_t* qp = Q + (size_t)(b * SEQL + q0 + (qc << 4) + l15) * MD + h * HDIM + (lg << 3);
    qa[qc][0] = *(const bf16x8*)qp;
    qa[qc][1] = *(const bf16x8*)(qp + 32);
  }

  // K staging (8 x 1KB chunks per tile, own wave only)
  const int o      = lane << 4;
  const int subrow = o >> 7;
  const int scb    = (o & 127) ^ ((subrow & 7) << 4);
  const char* Kbase = (const char*)K + (((size_t)(b * SEQL) * MD + h * HDIM) << 1);
  const unsigned short* VfB = (const unsigned short*)Vf + (size_t)((b << 4) + h) * 131072;

  f32x4 oacc[4][4] = {};
  float lrun[4] = {0.0f, 0.0f, 0.0f, 0.0f};
  const int swz = (l15 & 7) << 4;
  bf16x8 vreg[2][4];

  auto stageK = [&](int g, int buf) {
    char* dst = sK[wv][buf];
    const char* src = Kbase + (((size_t)(g << 6) * MD) << 1);
#pragma unroll
    for (int c = 0; c < 8; ++c)
      gload_lds16(src + (((size_t)((c << 3) + subrow) * MD) << 1) + scb, dst + c * 1024);
  };
  auto loadV = [&](int g) {
#pragma unroll
    for (int s = 0; s < 2; ++s)
#pragma unroll
      for (int df = 0; df < 4; ++df)
        vreg[s][df] = *(const bf16x8*)(VfB + ((size_t)(((g << 1) + s) << 2) + df) * 512 + (lane << 3));
  };

  stageK(wv, 0);      // global tile wv
  loadV(wv);

  for (int i = 0; i < 16; ++i) {
    const int g   = (i << 1) + wv;
    const int buf = i & 1;
    if (i < 15) stageK(g + 2, buf ^ 1);

    // wait K(i): FIFO outstanding = [K(i)8, V(i)8, K(i+1)8?] -> keep 16 (or 8 on last)
    if (i < 15) { asm volatile("s_waitcnt vmcnt(16)" ::: "memory"); }
    else        { asm volatile("s_waitcnt vmcnt(8)"  ::: "memory"); }
    __builtin_amdgcn_sched_barrier(0);

    // --- S^T = K . Q^T ---
    const char* kb = sK[wv][buf];
    f32x4 sacc[4][4];
#pragma unroll
    for (int qc = 0; qc < 4; ++qc)
#pragma unroll
      for (int f = 0; f < 4; ++f) sacc[qc][f] = (f32x4){0.f, 0.f, 0.f, 0.f};
#pragma unroll
    for (int s = 0; s < 2; ++s) {
      bf16x8 ka[4];
#pragma unroll
      for (int f = 0; f < 4; ++f) {
        int r  = (f << 4) + l15;
        int cb = ((lg << 4) + (s << 6)) ^ ((r & 7) << 4);
        ka[f] = *(const bf16x8*)(kb + (r << 7) + cb);
      }
      __builtin_amdgcn_s_setprio(1);
#pragma unroll
      for (int f = 0; f < 4; ++f)
#pragma unroll
        for (int qc = 0; qc < 4; ++qc)
          sacc[qc][f] = __builtin_amdgcn_mfma_f32_16x16x32_bf16(ka[f], qa[qc][s], sacc[qc][f], 0, 0, 0);
      __builtin_amdgcn_s_setprio(0);
    }

    // softmax for qc (writes P into ping-pong buffer qc&1)
    auto SM = [&](int qc) {
      char* pb = sPt[wv][qc & 1] + (l15 << 7);
#pragma unroll
      for (int f = 0; f < 4; ++f) {
        float p0 = exp2f(sacc[qc][f][0]);
        float p1 = exp2f(sacc[qc][f][1]);
        float p2 = exp2f(sacc[qc][f][2]);
        float p3 = exp2f(sacc[qc][f][3]);
        lrun[qc] += (p0 + p1) + (p2 + p3);
        uint2 pk2;
        pk2.x = cvtpk(p0, p1);
        pk2.y = cvtpk(p2, p3);
        *(uint2*)(pb + (((f << 5) + (lg << 3)) ^ swz)) = pk2;
      }
    };
    auto PV = [&](int qc) {
      char* pb = sPt[wv][qc & 1] + (l15 << 7);
#pragma unroll
      for (int s = 0; s < 2; ++s) {
        bf16x8 pa = *(const bf16x8*)(pb + (((lg << 4) + (s << 6)) ^ swz));
        __builtin_amdgcn_s_setprio(1);
#pragma unroll
        for (int df = 0; df < 4; ++df)
          oacc[qc][df] = __builtin_amdgcn_mfma_f32_16x16x32_bf16(pa, vreg[s][df], oacc[qc][df], 0, 0, 0);
        __builtin_amdgcn_s_setprio(0);
      }
    };

    SM(0); SM(1);
    // wait V(i) (arrives under SM work): outstanding = [V(i)8, K(i+1)8?]
    if (i < 15) { asm volatile("s_waitcnt vmcnt(8)" ::: "memory"); }
    else        { asm volatile("s_waitcnt vmcnt(0)" ::: "memory"); }
    __builtin_amdgcn_sched_barrier(0);
    PV(0); SM(2); PV(1); SM(3); PV(2); PV(3);

    if (i < 15) {
      __builtin_amdgcn_sched_barrier(0);   // keep V(i+1) loads AFTER PV consumed vreg
      loadV(g + 2);
    }
  }

  // intra-wave l reduce across lg groups
#pragma unroll
  for (int qc = 0; qc < 4; ++qc) {
    lrun[qc] += __shfl_xor(lrun[qc], 16);
    lrun[qc] += __shfl_xor(lrun[qc], 32);
  }

  // O-partials (f32 [64 d][256B q], XOR-swizzled) into own sK region (16KB)
  char* opart = (char*)sK[wv];
#pragma unroll
  for (int qc = 0; qc < 4; ++qc)
#pragma unroll
    for (int df = 0; df < 4; ++df) {
      int d  = (df << 4) + l15;
      int ob = (d << 8) + (((qc << 6) + (lg << 4)) ^ ((d & 7) << 4));
      *(f32x4*)(opart + ob) = oacc[qc][df];
    }
  if (lane < 16) {
#pragma unroll
    for (int qc = 0; qc < 4; ++qc) ((float*)sPt[wv])[(qc << 4) + l15] = lrun[qc];
  }
  __syncthreads();

  // cross-wave combine; each wave stores 2 q-frags
  const float nm = nmask[b];
  float linv[4];
#pragma unroll
  for (int qc = 0; qc < 4; ++qc) {
    float lo = ((const float*)sPt[wv ^ 1])[(qc << 4) + l15];
    linv[qc] = 1.0f / (lrun[qc] + lo - nm);
  }
#pragma unroll
  for (int j = 0; j < 2; ++j) {
    int qc = (wv << 1) + j;
#pragma unroll
    for (int df = 0; df < 4; ++df) {
      int d  = (df << 4) + l15;
      int ob = (d << 8) + (((qc << 6) + (lg << 4)) ^ ((d & 7) << 4));
      f32x4 a0 = *(const f32x4*)((const char*)sK[0] + ob);
      f32x4 a1 = *(const f32x4*)((const char*)sK[1] + ob);
#pragma unroll
      for (int r = 0; r < 4; ++r) {
        float lr = __shfl(linv[qc], (lg << 2) + r);
        int row = b * SEQL + q0 + (qc << 4) + (lg << 2) + r;
        O[(size_t)row * MD + h * HDIM + d] = (bf16_t)((a0[r] + a1[r]) * lr);
      }
    }
  }
}

// ---------------- launch ----------------
extern "C" void kernel_launch(void* const* d_in, const int* in_sizes, int n_in,
                              void* d_out, int out_size, void* d_ws, size_t ws_size,
                              hipStream_t stream) {
  const float* in_k = (const float*)d_in[0];
  const float* in_q = (const float*)d_in[1];
  const float* in_v = (const float*)d_in[2];
  const float* mask = (const float*)d_in[3];
  const float* Wq   = (const float*)d_in[4];
  const float* bq   = (const float*)d_in[5];
  const float* Wk   = (const float*)d_in[6];
  const float* bk   = (const float*)d_in[7];
  const float* Wv   = (const float*)d_in[8];
  const float* bv   = (const float*)d_in[9];
  const float* Wo   = (const float*)d_in[10];
  const float* bo   = (const float*)d_in[11];

  const size_t XN = (size_t)MROWS * MD;   // 4,194,304 elems
  const size_t WN = (size_t)MD * MD;      // 1,048,576 elems
  char* w = (char*)d_ws;
  size_t off = 0;
  auto alloc = [&](size_t bytes) { char* p = w + off; off += bytes; return p; };
  bf16_t* xq    = (bf16_t*)alloc(XN * 2);
  bf16_t* xk    = (bf16_t*)alloc(XN * 2);
  bf16_t* xv    = (bf16_t*)alloc(XN * 2);
  bf16_t* wqb   = (bf16_t*)alloc(WN * 2);
  bf16_t* wkb   = (bf16_t*)alloc(WN * 2);
  bf16_t* wvb   = (bf16_t*)alloc(WN * 2);
  bf16_t* wob   = (bf16_t*)alloc(WN * 2);
  bf16_t* Qp    = (bf16_t*)alloc(XN * 2);
  bf16_t* Kp    = (bf16_t*)alloc(XN * 2);
  bf16_t* Vfp   = (bf16_t*)alloc(XN * 2);  // V fragment layout
  float*  bqs   = (float*)alloc(MD * 4);
  float*  nmask = (float*)alloc(16);
  bf16_t* attn  = xq;  // alias: xq is dead after gemm_qkv
  (void)ws_size;

  // single consolidated convert (3 X + 4 W + bqs + nmask)
  cvt_all<<<16387, 256, 0, stream>>>(in_q, in_k, in_v, Wq, Wk, Wv, Wo, mask, bq,
                                     (unsigned short*)xq, (unsigned short*)xk, (unsigned short*)xv,
                                     (unsigned short*)wqb, (unsigned short*)wkb,
                                     (unsigned short*)wvb, (unsigned short*)wob, bqs, nmask);

  // fused QKV projection (combined, 768 blocks = 3/CU) — measured 71us config
  gemm_qkv<<<768, 256, 0, stream>>>(xq, xk, xv, wqb, wkb, wvb, bqs, bk, bv, mask, Qp, Kp, Vfp);

  // flash attention: 1024 blocks x 2 waves, KV-split, per-wave pipeline
  attn_kernel<<<1024, 128, 0, stream>>>(Qp, Kp, Vfp, nmask, attn);

  // output projection -> fp32 d_out
  gemm_out<<<256, 256, 0, stream>>>(attn, wob, bo, (float*)d_out);
}

// Round 12
// 144.123 us; speedup vs baseline: 1.5591x; 1.0003x over previous
//
#include <hip/hip_runtime.h>
#include <hip/hip_bf16.h>
#include <stdint.h>

// Problem dims (fixed)
#define MD    1024      // model dim
#define NHEAD 16
#define HDIM  64
#define BSZ   2
#define SEQL  2048
#define MROWS 4096      // BSZ*SEQL

#define SCL2E 0.18033688011112042f   // (1/sqrt(64)) * log2(e), folded into Wq/bq

typedef __bf16 bf16_t;
typedef __bf16  bf16x8 __attribute__((ext_vector_type(8)));
typedef float   f32x4  __attribute__((ext_vector_type(4)));

// Async global->LDS, 16B per lane. LDS dest is wave-uniform base (+lane*16 by HW).
__device__ __forceinline__ void gload_lds16(const void* g, void* l) {
  __builtin_amdgcn_global_load_lds((const __attribute__((address_space(1))) void*)g,
                                   (__attribute__((address_space(3))) void*)l,
                                   16, 0, 0);
}

__device__ __forceinline__ unsigned short f2bf(float f) {
  unsigned u = __builtin_bit_cast(unsigned, f);
  u += 0x7fffu + ((u >> 16) & 1u);          // round-to-nearest-even
  return (unsigned short)(u >> 16);
}

// packed 2xf32 -> 2xbf16 in one dword (src0 -> low half)
__device__ __forceinline__ unsigned cvtpk(float a, float b) {
  unsigned r;
  asm("v_cvt_pk_bf16_f32 %0, %1, %2" : "=v"(r) : "v"(a), "v"(b));
  return r;
}

// ---------------- consolidated convert ----------------
// grid 16387: [0,12288) X (4096 each), [12288,16384) W (1024 each; Wq scaled),
// 16384: bq*SCL2E -> bqs ; 16385/16386: nmask[b] = sum(1-mask[b][:])
__global__ __launch_bounds__(256)
void cvt_all(const float* __restrict__ q, const float* __restrict__ k, const float* __restrict__ v,
             const float* __restrict__ wq, const float* __restrict__ wk,
             const float* __restrict__ wv, const float* __restrict__ wo,
             const float* __restrict__ mask, const float* __restrict__ bq,
             unsigned short* __restrict__ xq, unsigned short* __restrict__ xk, unsigned short* __restrict__ xv,
             unsigned short* __restrict__ wqb, unsigned short* __restrict__ wkb,
             unsigned short* __restrict__ wvb, unsigned short* __restrict__ wob,
             float* __restrict__ bqs, float* __restrict__ nmask) {
  int bx = blockIdx.x;
  if (bx >= 16384) {
    if (bx == 16384) {                    // bqs = bq * SCL2E (1024 floats)
      int i = threadIdx.x;
      float4 val = ((const float4*)bq)[i];
      float4 o;
      o.x = val.x * SCL2E; o.y = val.y * SCL2E; o.z = val.z * SCL2E; o.w = val.w * SCL2E;
      ((float4*)bqs)[i] = o;
    } else {                              // nmask[b]
      int b = bx - 16385;
      const float* mp = mask + b * SEQL + threadIdx.x * 8;
      float s = 0.0f;
#pragma unroll
      for (int j = 0; j < 8; ++j) s += 1.0f - mp[j];
      for (int d = 1; d < 64; d <<= 1) s += __shfl_xor(s, d);
      __shared__ float wsum[4];
      if ((threadIdx.x & 63) == 0) wsum[threadIdx.x >> 6] = s;
      __syncthreads();
      if (threadIdx.x == 0) nmask[b] = wsum[0] + wsum[1] + wsum[2] + wsum[3];
    }
    return;
  }
  const float* in; unsigned short* out; int i;
  float scale = 1.0f;
  if (bx < 12288) {
    int t = bx >> 12;
    in  = (t == 0) ? q : (t == 1) ? k : v;
    out = (t == 0) ? xq : (t == 1) ? xk : xv;
    i = (bx & 4095) * 256 + threadIdx.x;
  } else {
    int t = (bx - 12288) >> 10;
    in  = (t == 0) ? wq : (t == 1) ? wk : (t == 2) ? wv : wo;
    out = (t == 0) ? wqb : (t == 1) ? wkb : (t == 2) ? wvb : wob;
    if (t == 0) scale = SCL2E;
    i = (bx & 1023) * 256 + threadIdx.x;
  }
  float4 val = ((const float4*)in)[i];
  ushort4 o;
  o.x = f2bf(val.x * scale); o.y = f2bf(val.y * scale);
  o.z = f2bf(val.z * scale); o.w = f2bf(val.w * scale);
  ((ushort4*)out)[i] = o;
}

// ---------------- GEMM: C[m,n] = sum_k A[m,k]*B[n,k] + bias[n] ----------------
// 128x128 tile, BK=64, 4 waves (2x2 of 64x64), 16x16x32 bf16 MFMA.
// LDS tiles [128 rows][128 bytes], XOR-swizzled via pre-swizzled global source.
// MODE: 0 = bf16 row-major [m][n], optional runtime row-mask;
//       1 = f32 row-major;
//       2 = bf16 V in PV-MFMA fragment layout, row-masked:
//           elem ofs = ((((b*16+h)*32+tile)*2+s2)*4+df)*512 + (lg*16+l15)*8 + j
//           (tile=kv>>6, s2=(kv>>5)&1, lg=(kv>>3)&3, j=kv&7, df=(d&63)>>4, l15=d&15)
template<int MODE>
__device__ __forceinline__ void gemm_body(const bf16_t* __restrict__ A,
                                          const bf16_t* __restrict__ Bm,
                                          const float*  __restrict__ bias,
                                          const float*  __restrict__ mask,
                                          void* __restrict__ Cout, int tile) {
  __shared__ __align__(1024) char sm[32768];
  char* lsA = sm;
  char* lsB = sm + 16384;
  const int tid  = threadIdx.x;
  const int lane = tid & 63;
  const int wv   = tid >> 6;
  const int wm   = wv >> 1, wn = wv & 1;
  const int m0   = (tile >> 3) << 7;   // 32 m-tiles
  const int n0   = (tile & 7)  << 7;   // 8 n-tiles
  const int l15  = lane & 15;
  const int g16  = (lane >> 4) << 4;   // k-group byte base

  f32x4 acc[4][4] = {};

  for (int kk = 0; kk < MD; kk += 64) {
#pragma unroll
    for (int i = 0; i < 4; ++i) {
      int ch  = (wv << 2) + i;
      int o   = ch * 1024 + (lane << 4);
      int row = o >> 7;
      int scb = (o & 127) ^ ((row & 7) << 4);   // pre-swizzled source column byte
      const char* gA = (const char*)A  + (((size_t)(m0 + row) * MD + kk) << 1) + scb;
      const char* gB = (const char*)Bm + (((size_t)(n0 + row) * MD + kk) << 1) + scb;
      gload_lds16(gA, lsA + ch * 1024);
      gload_lds16(gB, lsB + ch * 1024);
    }
    __syncthreads();
#pragma unroll
    for (int s = 0; s < 2; ++s) {
      bf16x8 af[4], bfv[4];
#pragma unroll
      for (int mi = 0; mi < 4; ++mi) {
        int r  = (wm << 6) + (mi << 4) + l15;
        int cb = (g16 + (s << 6)) ^ ((r & 7) << 4);
        af[mi] = *(const bf16x8*)(lsA + (r << 7) + cb);
      }
#pragma unroll
      for (int ni = 0; ni < 4; ++ni) {
        int r  = (wn << 6) + (ni << 4) + l15;
        int cb = (g16 + (s << 6)) ^ ((r & 7) << 4);
        bfv[ni] = *(const bf16x8*)(lsB + (r << 7) + cb);
      }
      __builtin_amdgcn_s_setprio(1);
#pragma unroll
      for (int mi = 0; mi < 4; ++mi)
#pragma unroll
        for (int ni = 0; ni < 4; ++ni)
          acc[mi][ni] = __builtin_amdgcn_mfma_f32_16x16x32_bf16(af[mi], bfv[ni], acc[mi][ni], 0, 0, 0);
      __builtin_amdgcn_s_setprio(0);
    }
    __syncthreads();
  }

  // epilogue: C/D layout col = lane&15, row = (lane>>4)*4 + reg
  float bvv[4];
#pragma unroll
  for (int ni = 0; ni < 4; ++ni) bvv[ni] = bias[n0 + (wn << 6) + (ni << 4) + l15];
#pragma unroll
  for (int mi = 0; mi < 4; ++mi) {
    int m = m0 + (wm << 6) + (mi << 4) + ((lane >> 4) << 2);  // token rows m..m+3
    float4 mk = {1.0f, 1.0f, 1.0f, 1.0f};
    if constexpr (MODE == 2) mk = *(const float4*)&mask[m];
    if constexpr (MODE == 0) { if (mask) mk = *(const float4*)&mask[m]; }
#pragma unroll
    for (int ni = 0; ni < 4; ++ni) {
      int col = n0 + (wn << 6) + (ni << 4) + l15;
      if constexpr (MODE == 2) {
        int bb   = m >> 11;
        int kv   = m & 2047;
        int tl   = kv >> 6;
        int s2   = (kv >> 5) & 1;
        int lgv  = (kv >> 3) & 3;
        int j0   = m & 4;
        int hh   = col >> 6;
        int dd   = col & 63;
        size_t e = ((((size_t)((bb << 4) + hh) * 32 + tl) * 2 + s2) * 4 + (dd >> 4)) * 512
                 + (size_t)(((lgv << 4) + (dd & 15)) << 3) + j0;
        ushort4 pk;
        pk.x = f2bf((acc[mi][ni][0] + bvv[ni]) * mk.x);
        pk.y = f2bf((acc[mi][ni][1] + bvv[ni]) * mk.y);
        pk.z = f2bf((acc[mi][ni][2] + bvv[ni]) * mk.z);
        pk.w = f2bf((acc[mi][ni][3] + bvv[ni]) * mk.w);
        *(ushort4*)((unsigned short*)Cout + e) = pk;
      } else {
#pragma unroll
        for (int r = 0; r < 4; ++r) {
          float vv = acc[mi][ni][r] + bvv[ni];
          if constexpr (MODE == 0) vv *= ((const float*)&mk)[r];
          if constexpr (MODE == 1) ((float*)Cout)[(size_t)(m + r) * MD + col] = vv;
          else                     ((bf16_t*)Cout)[(size_t)(m + r) * MD + col] = (bf16_t)vv;
        }
      }
    }
  }
}

// fused QKV (768 blocks, 3/CU, no swizzle): g selects (X,W,bias,Out).
// Q pre-scaled (bqs, mask=null), K row-masked, V fragment-layout + row-masked.
__global__ __launch_bounds__(256, 2)
void gemm_qkv(const bf16_t* __restrict__ xq, const bf16_t* __restrict__ xk, const bf16_t* __restrict__ xv,
              const bf16_t* __restrict__ wq, const bf16_t* __restrict__ wk, const bf16_t* __restrict__ wv_,
              const float* __restrict__ bqs, const float* __restrict__ bk, const float* __restrict__ bv,
              const float* __restrict__ mask,
              bf16_t* __restrict__ Qo, bf16_t* __restrict__ Ko, bf16_t* __restrict__ Vfo) {
  int t = blockIdx.x & 255;
  int g = blockIdx.x >> 8;
  if (g == 2) {
    gemm_body<2>(xv, wv_, bv, mask, Vfo, t);
  } else {
    const bf16_t* A  = (g == 0) ? xq : xk;
    const bf16_t* Bm = (g == 0) ? wq : wk;
    const float*  bi = (g == 0) ? bqs : bk;
    const float*  mk = (g == 0) ? nullptr : mask;
    bf16_t*       O  = (g == 0) ? Qo : Ko;
    gemm_body<0>(A, Bm, bi, mk, O, t);
  }
}

__global__ __launch_bounds__(256, 2)
void gemm_out(const bf16_t* __restrict__ A, const bf16_t* __restrict__ Bm,
              const float* __restrict__ bias, float* __restrict__ C) {
  gemm_body<1>(A, Bm, bias, nullptr, C, (int)blockIdx.x);
}

// ---------------- flash attention (R8 skeleton + V-in-reg + max TLP) --------
// grid 1024 = b(2)*h(16)*qtile(32) (XCD swizzle) = EXACTLY 4 blocks/CU, single
// balanced batch; block 256 = 4 waves x 16 q -> 16 waves/CU (4/SIMD), 2x the
// TLP of all prior variants. K staged in shared LDS dbuf via global_load_lds
// (swizzled source), ONE barrier per tile; V loaded to REGISTERS from the
// fragment-layout Vf tensor (coalesced lane*16B), issued one tile ahead after
// PV consumed the current vreg (barrier drain covers the wait). P through
// per-wave LDS (2KB each). LDS total 24KB. VGPR ~110 (no spills).
__global__ __launch_bounds__(256, 4)
void attn_kernel(const bf16_t* __restrict__ Q, const bf16_t* __restrict__ K,
                 const bf16_t* __restrict__ Vf, const float* __restrict__ nmask,
                 bf16_t* __restrict__ O) {
  __shared__ __align__(1024) char sK[2][8192];
  __shared__ __align__(1024) char sPt[8192];
  int bid = (int)blockIdx.x;
  int lb  = (bid & 7) * 128 + (bid >> 3);   // 1024 = 8 x 128, bijective
  const int tid  = threadIdx.x;
  const int lane = tid & 63;
  const int wv   = tid >> 6;
  const int qt   = lb & 31;
  const int h    = (lb >> 5) & 15;
  const int b    = lb >> 9;
  const int q0   = qt << 6;
  const int l15  = lane & 15;
  const int lg   = lane >> 4;

  // Q fragment (B-operand): lane q col = l15, d = lg*8+j (+32*s)
  bf16x8 qa[2];
  {
    const bf16_t* qp = Q + (size_t)(b * SEQL + q0 + (wv << 4) + l15) * MD + h * HDIM + (lg << 3);
    qa[0] = *(const bf16x8*)qp;
    qa[1] = *(const bf16x8*)(qp + 32);
  }

  // K staging addresses (per thread): 2 x 1KB chunks (8 chunks / 4 waves)
  const int ch0  = wv << 1;
  const int o0   = ch0 * 1024 + (lane << 4);
  const int row0 = o0 >> 7;
  const int scb0 = (o0 & 127) ^ ((row0 & 7) << 4);
  const int row1 = row0 + 8;
  const int scb1 = (o0 & 127) ^ ((row1 & 7) << 4);
  const char* Kbase = (const char*)K + (((size_t)(b * SEQL) * MD + h * HDIM) << 1);
  const unsigned short* VfB = (const unsigned short*)Vf + (size_t)((b << 4) + h) * 131072;

  f32x4 oacc[4] = {};
  float lrun = 0.0f;
  char* sPtW = sPt + (wv << 11);           // 2KB per wave (16 rows x 128B)
  const int swz = (l15 & 7) << 4;
  bf16x8 vreg[2][4];

  auto stageK = [&](int kv0, int bsel) {
    gload_lds16(Kbase + (((size_t)(kv0 + row0) * MD) << 1) + scb0, sK[bsel] + ch0 * 1024);
    gload_lds16(Kbase + (((size_t)(kv0 + row1) * MD) << 1) + scb1, sK[bsel] + ch0 * 1024 + 1024);
  };
  auto loadV = [&](int t) {
#pragma unroll
    for (int s = 0; s < 2; ++s)
#pragma unroll
      for (int df = 0; df < 4; ++df)
        vreg[s][df] = *(const bf16x8*)(VfB + ((size_t)(((t << 1) + s) << 2) + df) * 512 + (lane << 3));
  };

  stageK(0, 0);
  loadV(0);
  __syncthreads();

  for (int t = 0; t < SEQL / 64; ++t) {
    const int bsel = t & 1;
    if (t + 1 < SEQL / 64) stageK((t + 1) << 6, bsel ^ 1);

    const char* kb = sK[bsel];

    // --- S^T = K . Q^T : rows = kv, cols = q ---
    f32x4 sacc[4] = {};
#pragma unroll
    for (int s = 0; s < 2; ++s) {
      bf16x8 ka[4];
#pragma unroll
      for (int f = 0; f < 4; ++f) {
        int r  = (f << 4) + l15;
        int cb = ((lg << 4) + (s << 6)) ^ ((r & 7) << 4);
        ka[f] = *(const bf16x8*)(kb + (r << 7) + cb);
      }
      __builtin_amdgcn_s_setprio(1);
#pragma unroll
      for (int f = 0; f < 4; ++f)
        sacc[f] = __builtin_amdgcn_mfma_f32_16x16x32_bf16(ka[f], qa[s], sacc[f], 0, 0, 0);
      __builtin_amdgcn_s_setprio(0);
    }

    // --- p = exp2(z), pack to bf16, one ds_write_b64 per f ---
    {
      char* pbase = sPtW + (l15 << 7);
#pragma unroll
      for (int f = 0; f < 4; ++f) {
        float p0 = exp2f(sacc[f][0]);
        float p1 = exp2f(sacc[f][1]);
        float p2 = exp2f(sacc[f][2]);
        float p3 = exp2f(sacc[f][3]);
        lrun += (p0 + p1) + (p2 + p3);
        uint2 pk2;
        pk2.x = cvtpk(p0, p1);
        pk2.y = cvtpk(p2, p3);
        *(uint2*)(pbase + (((f << 5) + (lg << 3)) ^ swz)) = pk2;
      }
    }

    // --- PV: O[q][d] += Pt[q][kv] * V (V from registers) ---
#pragma unroll
    for (int s = 0; s < 2; ++s) {
      bf16x8 pa = *(const bf16x8*)(sPtW + (l15 << 7) + (((lg << 4) + (s << 6)) ^ swz));
      __builtin_amdgcn_s_setprio(1);
#pragma unroll
      for (int df = 0; df < 4; ++df)
        oacc[df] = __builtin_amdgcn_mfma_f32_16x16x32_bf16(pa, vreg[s][df], oacc[df], 0, 0, 0);
      __builtin_amdgcn_s_setprio(0);
    }

    // next tile's V into regs (after PV consumed vreg); barrier drain covers wait
    if (t + 1 < SEQL / 64) loadV(t + 1);
    __syncthreads();
  }

  // denominator: cross-lane reduce, subtract masked-count correction
  float nm = nmask[b];
  lrun += __shfl_xor(lrun, 16);
  lrun += __shfl_xor(lrun, 32);
  float linv = 1.0f / (lrun - nm);
#pragma unroll
  for (int r = 0; r < 4; ++r) {
    float lr = __shfl(linv, (lg << 2) + r);
    int row = b * SEQL + q0 + (wv << 4) + (lg << 2) + r;
#pragma unroll
    for (int df = 0; df < 4; ++df)
      O[(size_t)row * MD + h * HDIM + (df << 4) + l15] = (bf16_t)(oacc[df][r] * lr);
  }
}

// ---------------- launch ----------------
extern "C" void kernel_launch(void* const* d_in, const int* in_sizes, int n_in,
                              void* d_out, int out_size, void* d_ws, size_t ws_size,
                              hipStream_t stream) {
  const float* in_k = (const float*)d_in[0];
  const float* in_q = (const float*)d_in[1];
  const float* in_v = (const float*)d_in[2];
  const float* mask = (const float*)d_in[3];
  const float* Wq   = (const float*)d_in[4];
  const float* bq   = (const float*)d_in[5];
  const float* Wk   = (const float*)d_in[6];
  const float* bk   = (const float*)d_in[7];
  const float* Wv   = (const float*)d_in[8];
  const float* bv   = (const float*)d_in[9];
  const float* Wo   = (const float*)d_in[10];
  const float* bo   = (const float*)d_in[11];

  const size_t XN = (size_t)MROWS * MD;   // 4,194,304 elems
  const size_t WN = (size_t)MD * MD;      // 1,048,576 elems
  char* w = (char*)d_ws;
  size_t off = 0;
  auto alloc = [&](size_t bytes) { char* p = w + off; off += bytes; return p; };
  bf16_t* xq    = (bf16_t*)alloc(XN * 2);
  bf16_t* xk    = (bf16_t*)alloc(XN * 2);
  bf16_t* xv    = (bf16_t*)alloc(XN * 2);
  bf16_t* wqb   = (bf16_t*)alloc(WN * 2);
  bf16_t* wkb   = (bf16_t*)alloc(WN * 2);
  bf16_t* wvb   = (bf16_t*)alloc(WN * 2);
  bf16_t* wob   = (bf16_t*)alloc(WN * 2);
  bf16_t* Qp    = (bf16_t*)alloc(XN * 2);
  bf16_t* Kp    = (bf16_t*)alloc(XN * 2);
  bf16_t* Vfp   = (bf16_t*)alloc(XN * 2);  // V fragment layout
  float*  bqs   = (float*)alloc(MD * 4);
  float*  nmask = (float*)alloc(16);
  bf16_t* attn  = xq;  // alias: xq is dead after gemm_qkv
  (void)ws_size;

  // single consolidated convert (3 X + 4 W + bqs + nmask)
  cvt_all<<<16387, 256, 0, stream>>>(in_q, in_k, in_v, Wq, Wk, Wv, Wo, mask, bq,
                                     (unsigned short*)xq, (unsigned short*)xk, (unsigned short*)xv,
                                     (unsigned short*)wqb, (unsigned short*)wkb,
                                     (unsigned short*)wvb, (unsigned short*)wob, bqs, nmask);

  // fused QKV projection (combined, 768 blocks = 3/CU) — measured 71us config
  gemm_qkv<<<768, 256, 0, stream>>>(xq, xk, xv, wqb, wkb, wvb, bqs, bk, bv, mask, Qp, Kp, Vfp);

  // flash attention: 1024 blocks x 4 waves x 16 q, V-in-reg, 4 blocks/CU
  attn_kernel<<<1024, 256, 0, stream>>>(Qp, Kp, Vfp, nmask, attn);

  // output projection -> fp32 d_out
  gemm_out<<<256, 256, 0, stream>>>(attn, wob, bo, (float*)d_out);
}